// Round 2
// baseline (661.954 us; speedup 1.0000x reference)
//
#include <hip/hip_runtime.h>
#include <cstdint>
#include <cstddef>

typedef __bf16 bf16_t;
typedef __attribute__((ext_vector_type(4))) __bf16 bf16x4_t;
typedef __attribute__((ext_vector_type(8))) __bf16 bf16x8_t;
typedef __attribute__((ext_vector_type(16))) float f32x16_t;

#define T_TOK   4096
#define IN_DIM  4096
#define OUT_DIM 4096
#define N1      4352   // OUT_DIM + 256 svh rows (= 34 * 128 exactly)
#define K2      288    // 256 hk cols + 8 bias cols + 24 zero pad (9 * 32)
#define KSPLIT  8

__device__ __forceinline__ void gload_lds16(const bf16_t* g, bf16_t* l) {
  __builtin_amdgcn_global_load_lds(
      (__attribute__((address_space(1))) void*)(g),
      (__attribute__((address_space(3))) void*)(l), 16, 0, 0);
}

// ---------------- fp32 -> bf16 cast (memory-bound, float4-vectorized) -------
__global__ __launch_bounds__(256) void cast_kernel(const float* __restrict__ src,
                                                   bf16_t* __restrict__ dst) {
  size_t i = ((size_t)blockIdx.x * 256 + threadIdx.x) * 4;
  float4 v = *(const float4*)(src + i);
  bf16x4_t o;
  o[0] = (__bf16)v.x; o[1] = (__bf16)v.y; o[2] = (__bf16)v.z; o[3] = (__bf16)v.w;
  *(bf16x4_t*)(dst + i) = o;
}

// ---------------- fp32 gate matmul, split-K partials (router precision) -----
__global__ __launch_bounds__(256) void gate_partial(const float* __restrict__ x,
                                                    const float* __restrict__ g,
                                                    float* __restrict__ part) {
  __shared__ __align__(16) float Xs[64 * 68];
  __shared__ __align__(16) float Gs[64 * 68];
  const int tid = threadIdx.x;
  const int tbase = blockIdx.x * 64;
  const int kbase = blockIdx.y * (IN_DIM / KSPLIT);
  const int tg = tid & 15;
  const int rg = tid >> 4;
  float acc[4][4] = {{0.f}};

  for (int cc = 0; cc < (IN_DIM / KSPLIT) / 64; ++cc) {
    const int kc = kbase + cc * 64;
    __syncthreads();
#pragma unroll
    for (int j = 0; j < 4; ++j) {
      const int f = tid * 16 + j * 4;
      const int tt = f >> 6, k4 = f & 63;
      float4 xv = *(const float4*)&x[(size_t)(tbase + tt) * IN_DIM + kc + k4];
      Xs[(k4 + 0) * 68 + tt] = xv.x; Xs[(k4 + 1) * 68 + tt] = xv.y;
      Xs[(k4 + 2) * 68 + tt] = xv.z; Xs[(k4 + 3) * 68 + tt] = xv.w;
      float4 gv = *(const float4*)&g[(size_t)tt * IN_DIM + kc + k4];
      Gs[(k4 + 0) * 68 + tt] = gv.x; Gs[(k4 + 1) * 68 + tt] = gv.y;
      Gs[(k4 + 2) * 68 + tt] = gv.z; Gs[(k4 + 3) * 68 + tt] = gv.w;
    }
    __syncthreads();
#pragma unroll 4
    for (int kk = 0; kk < 64; ++kk) {
      float4 xv = *(const float4*)&Xs[kk * 68 + tg * 4];
      float4 gv = *(const float4*)&Gs[kk * 68 + rg * 4];
      float xa[4] = {xv.x, xv.y, xv.z, xv.w};
      float ga[4] = {gv.x, gv.y, gv.z, gv.w};
#pragma unroll
      for (int i = 0; i < 4; ++i)
#pragma unroll
        for (int j = 0; j < 4; ++j) acc[i][j] = fmaf(xa[i], ga[j], acc[i][j]);
    }
  }
#pragma unroll
  for (int i = 0; i < 4; ++i) {
    float4 o4 = make_float4(acc[i][0], acc[i][1], acc[i][2], acc[i][3]);
    *(float4*)&part[((size_t)blockIdx.y * T_TOK + tbase + tg * 4 + i) * 64 + rg * 4] = o4;
  }
}

// ---------------- router: L2-norm logits, top-2 softmax, dense weights ------
__global__ __launch_bounds__(64) void router_kernel(const float* __restrict__ part,
                                                    float* __restrict__ wts) {
  const int t = blockIdx.x * 64 + threadIdx.x;
  float rl2[8];
#pragma unroll
  for (int e = 0; e < 8; ++e) rl2[e] = 0.f;
#pragma unroll
  for (int r4 = 0; r4 < 16; ++r4) {
    float4 s = make_float4(0.f, 0.f, 0.f, 0.f);
    for (int ks = 0; ks < KSPLIT; ++ks) {
      float4 p = *(const float4*)&part[((size_t)ks * T_TOK + t) * 64 + r4 * 4];
      s.x += p.x; s.y += p.y; s.z += p.z; s.w += p.w;
    }
    rl2[r4 >> 1] += s.x * s.x + s.y * s.y + s.z * s.z + s.w * s.w;
  }
  float rl[8];
#pragma unroll
  for (int e = 0; e < 8; ++e) rl[e] = sqrtf(rl2[e]);
  int e1 = 0; float v1 = rl[0];
#pragma unroll
  for (int e = 1; e < 8; ++e) if (rl[e] > v1) { v1 = rl[e]; e1 = e; }
  int e2 = -1; float v2 = -1e30f;
#pragma unroll
  for (int e = 0; e < 8; ++e) if (e != e1 && rl[e] > v2) { v2 = rl[e]; e2 = e; }
  float w1 = 1.f / (1.f + expf(v2 - v1));
  float o[8];
#pragma unroll
  for (int e = 0; e < 8; ++e) o[e] = 0.f;
  o[e1] = w1; o[e2] = 1.f - w1;
  *(float4*)&wts[(size_t)t * 8 + 0] = make_float4(o[0], o[1], o[2], o[3]);
  *(float4*)&wts[(size_t)t * 8 + 4] = make_float4(o[4], o[5], o[6], o[7]);
}

// ---------------- A2 = [hk * w_e | w_e | 0pad] in bf16 ----------------------
__global__ __launch_bounds__(256) void build_a2(const float* __restrict__ hk,
                                                const float* __restrict__ wts,
                                                bf16_t* __restrict__ A2) {
  const int t = blockIdx.x;
  for (int c = threadIdx.x; c < K2; c += 256) {
    float v;
    if (c < 256)      v = hk[(size_t)t * 256 + c] * wts[(size_t)t * 8 + (c >> 5)];
    else if (c < 264) v = wts[(size_t)t * 8 + (c - 256)];
    else              v = 0.f;
    A2[(size_t)t * K2 + c] = (__bf16)v;
  }
}

// ---------------- B2t[o][c] = u[e][o][k] (c=e*32+k) | bias[e][o] | 0 --------
__global__ __launch_bounds__(256) void build_b2t(const float* __restrict__ u,
                                                 const float* __restrict__ eb,
                                                 bf16_t* __restrict__ B2t) {
  const int o = blockIdx.x;
  for (int c = threadIdx.x; c < K2; c += 256) {
    float v;
    if (c < 256)      v = u[((size_t)(c >> 5) * OUT_DIM + o) * 32 + (c & 31)];
    else if (c < 264) v = eb[(size_t)(c - 256) * OUT_DIM + o];
    else              v = 0.f;
    B2t[(size_t)o * K2 + c] = (__bf16)v;
  }
}

// ---------------- bf16 MFMA GEMM: C[m,n] = sum_k A[m,k]*Bt[n,k] -------------
// Block tile 256x128, 4 waves in 2x2, wave-tile 128x64 (4x2 of 32x32),
// mfma_f32_32x32x16_bf16, BK=32, global_load_lds x16 staging.
// 43.7 FLOP per LDS byte (vs 32.8 for the 64x64 wave-tile) -> lifts the
// ds_read_b128 throughput bound that capped round-1 at 24% MfmaUtil.
// MODE 0: n<4096 -> out[m][n]=acc+bias[n]; else hk[m][n-4096]=acc   (gemm1)
// MODE 1: out[m][n] += acc                                          (gemm2)
template <int MODE>
__global__ __launch_bounds__(256) void gemm_bt(const bf16_t* __restrict__ A,
                                               const bf16_t* __restrict__ Bt,
                                               int K, int lda, int ldb,
                                               float* __restrict__ out,
                                               const float* __restrict__ bias,
                                               float* __restrict__ hk) {
  __shared__ __align__(16) bf16_t As[256 * 32];  // 16 KB
  __shared__ __align__(16) bf16_t Bs[128 * 32];  // 8 KB
  const int tid = threadIdx.x;
  const int wave = tid >> 6, lane = tid & 63;
  const int mBase = blockIdx.y * 256, nBase = blockIdx.x * 128;
  const int wm = wave >> 1, wn = wave & 1;   // wave grid 2(M) x 2(N)
  const int srow = lane >> 2, scol = (lane & 3) * 8;  // staging: 16 rows x 64B
  const int r32 = lane & 31, khalf = (lane >> 5) * 8;

  f32x16_t acc[4][2];
#pragma unroll
  for (int t = 0; t < 4; ++t)
#pragma unroll
    for (int s = 0; s < 2; ++s)
#pragma unroll
      for (int r = 0; r < 16; ++r) acc[t][s][r] = 0.f;

  // each wave stages 64 rows of A (4 instr) and 32 rows of B (2 instr)
  const bf16_t* gA = A + (size_t)(mBase + wave * 64 + srow) * lda + scol;
  const bf16_t* gB = Bt + (size_t)(nBase + wave * 32 + srow) * ldb + scol;
  bf16_t* lA = &As[(wave * 64) * 32];
  bf16_t* lB = &Bs[(wave * 32) * 32];

  for (int k0 = 0; k0 < K; k0 += 32) {
    gload_lds16(gA + k0, lA);
    gload_lds16(gA + k0 + (size_t)16 * lda, lA + 16 * 32);
    gload_lds16(gA + k0 + (size_t)32 * lda, lA + 32 * 32);
    gload_lds16(gA + k0 + (size_t)48 * lda, lA + 48 * 32);
    gload_lds16(gB + k0, lB);
    gload_lds16(gB + k0 + (size_t)16 * ldb, lB + 16 * 32);
    __syncthreads();   // drains vmcnt (global_load_lds) + orders LDS
#pragma unroll
    for (int kk = 0; kk < 2; ++kk) {
      bf16x8_t a[4], b[2];
#pragma unroll
      for (int t = 0; t < 4; ++t)
        a[t] = *(const bf16x8_t*)&As[(wm * 128 + t * 32 + r32) * 32 + kk * 16 + khalf];
#pragma unroll
      for (int s = 0; s < 2; ++s)
        b[s] = *(const bf16x8_t*)&Bs[(wn * 64 + s * 32 + r32) * 32 + kk * 16 + khalf];
#pragma unroll
      for (int t = 0; t < 4; ++t)
#pragma unroll
        for (int s = 0; s < 2; ++s)
          acc[t][s] = __builtin_amdgcn_mfma_f32_32x32x16_bf16(a[s ? t : t], b[s], acc[t][s], 0, 0, 0);
    }
    __syncthreads();   // protect LDS before next staging
  }

  // C/D 32x32 layout: col = lane&31, row = (reg&3) + 8*(reg>>2) + 4*(lane>>5)
  const int rquad = 4 * (lane >> 5);
#pragma unroll
  for (int t = 0; t < 4; ++t) {
    const int rbase = mBase + wm * 128 + t * 32 + rquad;
#pragma unroll
    for (int s = 0; s < 2; ++s) {
      const int n = nBase + wn * 64 + s * 32 + r32;
      if (MODE == 0) {
        if (nBase < OUT_DIM) {   // block-uniform branch
          const float bn = bias[n];
#pragma unroll
          for (int r = 0; r < 16; ++r) {
            const int row = rbase + (r & 3) + 8 * (r >> 2);
            out[(size_t)row * OUT_DIM + n] = acc[t][s][r] + bn;
          }
        } else {
#pragma unroll
          for (int r = 0; r < 16; ++r) {
            const int row = rbase + (r & 3) + 8 * (r >> 2);
            hk[(size_t)row * 256 + (n - OUT_DIM)] = acc[t][s][r];
          }
        }
      } else {
#pragma unroll
        for (int r = 0; r < 16; ++r) {
          const int row = rbase + (r & 3) + 8 * (r >> 2);
          out[(size_t)row * OUT_DIM + n] += acc[t][s][r];
        }
      }
    }
  }
}

extern "C" void kernel_launch(void* const* d_in, const int* in_sizes, int n_in,
                              void* d_out, int out_size, void* d_ws, size_t ws_size,
                              hipStream_t stream) {
  const float* x   = (const float*)d_in[0];  // [T, IN]
  const float* gw  = (const float*)d_in[1];  // [64, IN]
  const float* sw  = (const float*)d_in[2];  // [OUT, IN]
  const float* sb  = (const float*)d_in[3];  // [OUT]
  const float* u   = (const float*)d_in[4];  // [E, OUT, 32]
  const float* svh = (const float*)d_in[5];  // [E, 32, IN] == [256, IN]
  const float* eb  = (const float*)d_in[6];  // [E, OUT]
  float* out = (float*)d_out;

  char* ws = (char*)d_ws;
  size_t off = 0;
  auto carve = [&](size_t bytes) {
    void* p = ws + off;
    off = (off + bytes + 255) & ~(size_t)255;
    return p;
  };
  bf16_t* Xbf  = (bf16_t*)carve((size_t)T_TOK * IN_DIM * 2);
  bf16_t* Wbf  = (bf16_t*)carve((size_t)N1 * IN_DIM * 2);
  float*  hk   = (float*)carve((size_t)T_TOK * 256 * 4);
  float*  part = (float*)carve((size_t)KSPLIT * T_TOK * 64 * 4);
  float*  wts  = (float*)carve((size_t)T_TOK * 8 * 4);
  bf16_t* A2   = (bf16_t*)carve((size_t)T_TOK * K2 * 2);
  bf16_t* B2t  = (bf16_t*)carve((size_t)OUT_DIM * K2 * 2);
  (void)ws_size; (void)in_sizes; (void)n_in; (void)out_size;

  // casts: x -> Xbf ; [shared_w ; svh] -> Wbf (N1 = 4352 rows)
  cast_kernel<<<(T_TOK * IN_DIM) / 1024, 256, 0, stream>>>(x, Xbf);
  cast_kernel<<<(OUT_DIM * IN_DIM) / 1024, 256, 0, stream>>>(sw, Wbf);
  cast_kernel<<<(256 * IN_DIM) / 1024, 256, 0, stream>>>(svh, Wbf + (size_t)OUT_DIM * IN_DIM);

  // fp32 gate (router precision!) + topk weights
  gate_partial<<<dim3(T_TOK / 64, KSPLIT), 256, 0, stream>>>(x, gw, part);
  router_kernel<<<T_TOK / 64, 64, 0, stream>>>(part, wts);

  // expert second-stage weight matrix (independent of gemm1)
  build_b2t<<<OUT_DIM, 256, 0, stream>>>(u, eb, B2t);

  // GEMM1: [T,4096] x [4352,4096]^T -> pretrained(+bias) into d_out, hk into ws
  gemm_bt<0><<<dim3(N1 / 128, T_TOK / 256), 256, 0, stream>>>(
      Xbf, Wbf, IN_DIM, IN_DIM, IN_DIM, out, sb, hk);

  // A2 = [hk*w | w | 0], then GEMM2 accumulates expert output into d_out
  build_a2<<<T_TOK, 256, 0, stream>>>(hk, wts, A2);
  gemm_bt<1><<<dim3(OUT_DIM / 128, T_TOK / 256), 256, 0, stream>>>(
      A2, B2t, K2, K2, K2, out, nullptr, nullptr);
}

// Round 3
// 475.841 us; speedup vs baseline: 1.3911x; 1.3911x over previous
//
#include <hip/hip_runtime.h>
#include <cstdint>
#include <cstddef>

typedef __bf16 bf16_t;
typedef __attribute__((ext_vector_type(4))) __bf16 bf16x4_t;
typedef __attribute__((ext_vector_type(8))) __bf16 bf16x8_t;
typedef __attribute__((ext_vector_type(4))) float f32x4_t;

#define T_TOK   4096
#define IN_DIM  4096
#define OUT_DIM 4096
#define N1      4352   // OUT_DIM + 256 svh rows (= 34 * 128 exactly)
#define K2      288    // 256 hk cols + 8 bias cols + 24 zero pad (9 * 32)
#define KSPLIT  8

__device__ __forceinline__ void gload_lds16(const bf16_t* g, bf16_t* l) {
  __builtin_amdgcn_global_load_lds(
      (__attribute__((address_space(1))) void*)(g),
      (__attribute__((address_space(3))) void*)(l), 16, 0, 0);
}

// ---------------- fused fp32 -> bf16 casts: x->Xbf, [sw;svh]->Wbf -----------
#define XSZ ((size_t)T_TOK * IN_DIM)
#define WSZ ((size_t)OUT_DIM * IN_DIM)
#define VSZ ((size_t)256 * IN_DIM)
__global__ __launch_bounds__(256) void cast_all(const float* __restrict__ x,
                                                const float* __restrict__ sw,
                                                const float* __restrict__ svh,
                                                bf16_t* __restrict__ Xbf,
                                                bf16_t* __restrict__ Wbf) {
  size_t idx = ((size_t)blockIdx.x * 256 + threadIdx.x) * 4;
  const float* src; bf16_t* dst; size_t i;
  if (idx < XSZ)            { src = x;   dst = Xbf;       i = idx; }
  else if (idx < XSZ + WSZ) { src = sw;  dst = Wbf;       i = idx - XSZ; }
  else                      { src = svh; dst = Wbf + WSZ; i = idx - XSZ - WSZ; }
  float4 v = *(const float4*)(src + i);
  bf16x4_t o;
  o[0] = (__bf16)v.x; o[1] = (__bf16)v.y; o[2] = (__bf16)v.z; o[3] = (__bf16)v.w;
  *(bf16x4_t*)(dst + i) = o;
}

// ---------------- fp32 gate matmul, split-K partials (router precision) -----
__global__ __launch_bounds__(256) void gate_partial(const float* __restrict__ x,
                                                    const float* __restrict__ g,
                                                    float* __restrict__ part) {
  __shared__ __align__(16) float Xs[64 * 68];
  __shared__ __align__(16) float Gs[64 * 68];
  const int tid = threadIdx.x;
  const int tbase = blockIdx.x * 64;
  const int kbase = blockIdx.y * (IN_DIM / KSPLIT);
  const int tg = tid & 15;
  const int rg = tid >> 4;
  float acc[4][4] = {{0.f}};

  for (int cc = 0; cc < (IN_DIM / KSPLIT) / 64; ++cc) {
    const int kc = kbase + cc * 64;
    __syncthreads();
#pragma unroll
    for (int j = 0; j < 4; ++j) {
      const int f = tid * 16 + j * 4;
      const int tt = f >> 6, k4 = f & 63;
      float4 xv = *(const float4*)&x[(size_t)(tbase + tt) * IN_DIM + kc + k4];
      Xs[(k4 + 0) * 68 + tt] = xv.x; Xs[(k4 + 1) * 68 + tt] = xv.y;
      Xs[(k4 + 2) * 68 + tt] = xv.z; Xs[(k4 + 3) * 68 + tt] = xv.w;
      float4 gv = *(const float4*)&g[(size_t)tt * IN_DIM + kc + k4];
      Gs[(k4 + 0) * 68 + tt] = gv.x; Gs[(k4 + 1) * 68 + tt] = gv.y;
      Gs[(k4 + 2) * 68 + tt] = gv.z; Gs[(k4 + 3) * 68 + tt] = gv.w;
    }
    __syncthreads();
#pragma unroll 4
    for (int kk = 0; kk < 64; ++kk) {
      float4 xv = *(const float4*)&Xs[kk * 68 + tg * 4];
      float4 gv = *(const float4*)&Gs[kk * 68 + rg * 4];
      float xa[4] = {xv.x, xv.y, xv.z, xv.w};
      float ga[4] = {gv.x, gv.y, gv.z, gv.w};
#pragma unroll
      for (int i = 0; i < 4; ++i)
#pragma unroll
        for (int j = 0; j < 4; ++j) acc[i][j] = fmaf(xa[i], ga[j], acc[i][j]);
    }
  }
#pragma unroll
  for (int i = 0; i < 4; ++i) {
    float4 o4 = make_float4(acc[i][0], acc[i][1], acc[i][2], acc[i][3]);
    *(float4*)&part[((size_t)blockIdx.y * T_TOK + tbase + tg * 4 + i) * 64 + rg * 4] = o4;
  }
}

// ---------------- router: L2-norm logits, top-2 softmax, dense weights ------
__global__ __launch_bounds__(64) void router_kernel(const float* __restrict__ part,
                                                    float* __restrict__ wts) {
  const int t = blockIdx.x * 64 + threadIdx.x;
  float rl2[8];
#pragma unroll
  for (int e = 0; e < 8; ++e) rl2[e] = 0.f;
#pragma unroll
  for (int r4 = 0; r4 < 16; ++r4) {
    float4 s = make_float4(0.f, 0.f, 0.f, 0.f);
    for (int ks = 0; ks < KSPLIT; ++ks) {
      float4 p = *(const float4*)&part[((size_t)ks * T_TOK + t) * 64 + r4 * 4];
      s.x += p.x; s.y += p.y; s.z += p.z; s.w += p.w;
    }
    rl2[r4 >> 1] += s.x * s.x + s.y * s.y + s.z * s.z + s.w * s.w;
  }
  float rl[8];
#pragma unroll
  for (int e = 0; e < 8; ++e) rl[e] = sqrtf(rl2[e]);
  int e1 = 0; float v1 = rl[0];
#pragma unroll
  for (int e = 1; e < 8; ++e) if (rl[e] > v1) { v1 = rl[e]; e1 = e; }
  int e2 = -1; float v2 = -1e30f;
#pragma unroll
  for (int e = 0; e < 8; ++e) if (e != e1 && rl[e] > v2) { v2 = rl[e]; e2 = e; }
  float w1 = 1.f / (1.f + expf(v2 - v1));
  float o[8];
#pragma unroll
  for (int e = 0; e < 8; ++e) o[e] = 0.f;
  o[e1] = w1; o[e2] = 1.f - w1;
  *(float4*)&wts[(size_t)t * 8 + 0] = make_float4(o[0], o[1], o[2], o[3]);
  *(float4*)&wts[(size_t)t * 8 + 4] = make_float4(o[4], o[5], o[6], o[7]);
}

// ------- fused build: blocks 0..4095 -> B2t rows; 4096..8191 -> A2 rows -----
// B2t[o][c] = u[e][o][k] (c=e*32+k) | bias[e][o] | 0pad
// A2[t][c]  = hk[t][c]*w_{t,e(c)}   | w_{t,0..7}  | 0pad   (runs after GEMM1)
__global__ __launch_bounds__(256) void build_ab(const float* __restrict__ u,
                                                const float* __restrict__ eb,
                                                const float* __restrict__ hk,
                                                const float* __restrict__ wts,
                                                bf16_t* __restrict__ A2,
                                                bf16_t* __restrict__ B2t) {
  const int b = blockIdx.x;
  if (b < OUT_DIM) {
    const int o = b;
    for (int c = threadIdx.x; c < K2; c += 256) {
      float v;
      if (c < 256)      v = u[((size_t)(c >> 5) * OUT_DIM + o) * 32 + (c & 31)];
      else if (c < 264) v = eb[(size_t)(c - 256) * OUT_DIM + o];
      else              v = 0.f;
      B2t[(size_t)o * K2 + c] = (__bf16)v;
    }
  } else {
    const int t = b - OUT_DIM;
    for (int c = threadIdx.x; c < K2; c += 256) {
      float v;
      if (c < 256)      v = hk[(size_t)t * 256 + c] * wts[(size_t)t * 8 + (c >> 5)];
      else if (c < 264) v = wts[(size_t)t * 8 + (c - 256)];
      else              v = 0.f;
      A2[(size_t)t * K2 + c] = (__bf16)v;
    }
  }
}

// ---------------- m97-style bf16 MFMA GEMM: C[m,n] = sum_k A[m,k]*Bt[n,k] ---
// 128x128 tile, BK=32, 256 thr = 4 waves (2x2 of 64x64), 16x16x32 MFMA,
// global_load_lds x16 staging.  (round-1 structure: 557 TF, conflicts 1.78e7)
// MODE 0 (gemm1, grid 34x32): XCD-locality swizzle — lid%8 picks the XCD
//   (round-robin dispatch heuristic); map n = (lid&7)*4 + (lid>>3)&3 so each
//   XCD re-reads only 4 B-tiles (4 MB, L2-resident) while A streams L3-hot.
//   Tail 64 blocks cover the two hk n-tiles (n=32,33).
//   Epilogue: n<4096 -> out = acc + bias[n]; else hk = acc.
// MODE 1 (gemm2, grid 32x32): natural map (gx=32 already XCD-aligned);
//   epilogue out += acc.
template <int MODE>
__global__ __launch_bounds__(256) void gemm_bt(const bf16_t* __restrict__ A,
                                               const bf16_t* __restrict__ Bt,
                                               int K, int lda, int ldb,
                                               float* __restrict__ out,
                                               const float* __restrict__ bias,
                                               float* __restrict__ hk) {
  __shared__ __align__(16) bf16_t As[128 * 32];
  __shared__ __align__(16) bf16_t Bs[128 * 32];
  const int tid = threadIdx.x;
  const int wave = tid >> 6, lane = tid & 63;

  int bx, by;
  if (MODE == 0) {
    const int lid = blockIdx.y * gridDim.x + blockIdx.x;
    if (lid < 1024) { bx = (lid & 7) * 4 + ((lid >> 3) & 3); by = lid >> 5; }
    else            { const int r = lid - 1024; bx = 32 + (r >> 5); by = r & 31; }
  } else {
    bx = blockIdx.x; by = blockIdx.y;
  }
  const int mBase = by * 128, nBase = bx * 128;

  const int wm = wave >> 1, wn = wave & 1;
  const int lr = lane & 15, lk = (lane >> 4) * 8;
  const int arow = lane >> 2, acol = (lane & 3) * 8;

  f32x4_t acc[4][4];
#pragma unroll
  for (int i = 0; i < 4; ++i)
#pragma unroll
    for (int j = 0; j < 4; ++j) {
      f32x4_t z = {0.f, 0.f, 0.f, 0.f};
      acc[i][j] = z;
    }

  const bf16_t* gA = A + (size_t)(mBase + wave * 32 + arow) * lda + acol;
  const bf16_t* gB = Bt + (size_t)(nBase + wave * 32 + arow) * ldb + acol;
  bf16_t* lA = &As[(wave * 32) * 32];
  bf16_t* lB = &Bs[(wave * 32) * 32];

  for (int k0 = 0; k0 < K; k0 += 32) {
    gload_lds16(gA + k0, lA);
    gload_lds16(gA + k0 + (size_t)16 * lda, lA + 16 * 32);
    gload_lds16(gB + k0, lB);
    gload_lds16(gB + k0 + (size_t)16 * ldb, lB + 16 * 32);
    __syncthreads();   // drains vmcnt (global_load_lds) + orders LDS
    bf16x8_t a[4], b[4];
#pragma unroll
    for (int mi = 0; mi < 4; ++mi)
      a[mi] = *(const bf16x8_t*)&As[(wm * 64 + mi * 16 + lr) * 32 + lk];
#pragma unroll
    for (int ni = 0; ni < 4; ++ni)
      b[ni] = *(const bf16x8_t*)&Bs[(wn * 64 + ni * 16 + lr) * 32 + lk];
#pragma unroll
    for (int mi = 0; mi < 4; ++mi)
#pragma unroll
      for (int ni = 0; ni < 4; ++ni)
        acc[mi][ni] = __builtin_amdgcn_mfma_f32_16x16x32_bf16(a[mi], b[ni], acc[mi][ni], 0, 0, 0);
    __syncthreads();   // protect LDS before next staging
  }

  const int row0 = (lane >> 4) * 4;  // C/D: col = lane&15, row = (lane>>4)*4 + r
#pragma unroll
  for (int mi = 0; mi < 4; ++mi) {
    const int m = mBase + wm * 64 + mi * 16 + row0;
#pragma unroll
    for (int ni = 0; ni < 4; ++ni) {
      const int n = nBase + wn * 64 + ni * 16 + lr;
      f32x4_t v = acc[mi][ni];
      if (MODE == 0) {
        if (n < OUT_DIM) {
          const float bn = bias[n];
#pragma unroll
          for (int r = 0; r < 4; ++r) out[(size_t)(m + r) * OUT_DIM + n] = v[r] + bn;
        } else {
#pragma unroll
          for (int r = 0; r < 4; ++r) hk[(size_t)(m + r) * 256 + (n - OUT_DIM)] = v[r];
        }
      } else {
#pragma unroll
        for (int r = 0; r < 4; ++r) out[(size_t)(m + r) * OUT_DIM + n] += v[r];
      }
    }
  }
}

extern "C" void kernel_launch(void* const* d_in, const int* in_sizes, int n_in,
                              void* d_out, int out_size, void* d_ws, size_t ws_size,
                              hipStream_t stream) {
  const float* x   = (const float*)d_in[0];  // [T, IN]
  const float* gw  = (const float*)d_in[1];  // [64, IN]
  const float* sw  = (const float*)d_in[2];  // [OUT, IN]
  const float* sb  = (const float*)d_in[3];  // [OUT]
  const float* u   = (const float*)d_in[4];  // [E, OUT, 32]
  const float* svh = (const float*)d_in[5];  // [E, 32, IN] == [256, IN]
  const float* eb  = (const float*)d_in[6];  // [E, OUT]
  float* out = (float*)d_out;

  char* ws = (char*)d_ws;
  size_t off = 0;
  auto carve = [&](size_t bytes) {
    void* p = ws + off;
    off = (off + bytes + 255) & ~(size_t)255;
    return p;
  };
  bf16_t* Xbf  = (bf16_t*)carve((size_t)T_TOK * IN_DIM * 2);
  bf16_t* Wbf  = (bf16_t*)carve((size_t)N1 * IN_DIM * 2);
  float*  hk   = (float*)carve((size_t)T_TOK * 256 * 4);
  float*  part = (float*)carve((size_t)KSPLIT * T_TOK * 64 * 4);
  float*  wts  = (float*)carve((size_t)T_TOK * 8 * 4);
  bf16_t* A2   = (bf16_t*)carve((size_t)T_TOK * K2 * 2);
  bf16_t* B2t  = (bf16_t*)carve((size_t)OUT_DIM * K2 * 2);
  (void)ws_size; (void)in_sizes; (void)n_in; (void)out_size;

  // single fused cast launch: x -> Xbf ; [shared_w ; svh] -> Wbf
  cast_all<<<(int)((XSZ + WSZ + VSZ) / 1024), 256, 0, stream>>>(x, sw, svh, Xbf, Wbf);

  // fp32 gate (router precision!) + topk weights
  gate_partial<<<dim3(T_TOK / 64, KSPLIT), 256, 0, stream>>>(x, gw, part);
  router_kernel<<<T_TOK / 64, 64, 0, stream>>>(part, wts);

  // GEMM1: [T,4096] x [4352,4096]^T -> pretrained(+bias) into d_out, hk into ws
  gemm_bt<0><<<dim3(N1 / 128, T_TOK / 128), 256, 0, stream>>>(
      Xbf, Wbf, IN_DIM, IN_DIM, IN_DIM, out, sb, hk);

  // fused build of B2t (u,bias fold) and A2 (hk * routed weight)
  build_ab<<<OUT_DIM + T_TOK, 256, 0, stream>>>(u, eb, hk, wts, A2, B2t);

  // GEMM2 accumulates expert output into d_out
  gemm_bt<1><<<dim3(OUT_DIM / 128, T_TOK / 128), 256, 0, stream>>>(
      A2, B2t, K2, K2, K2, out, nullptr, nullptr);
}